// Round 1
// baseline (4430.373 us; speedup 1.0000x reference)
//
#include <hip/hip_runtime.h>
#include <math.h>

// Problem constants
#define NL 4
#define DM 256
#define DI 512
#define DSTATE 16
#define DTRANK 16
#define DCONV 4
#define IN_FEAT 64
#define OUT_DIM 128
#define MID 50
#define NCLS 3
#define BB 16
#define LL 1024
#define T_TOK (BB*LL)   // 16384

__device__ __forceinline__ float silu_f(float x) {
    return x / (1.f + __expf(-x));
}
__device__ __forceinline__ float softplus_f(float x) {
    return (x > 20.f) ? x : log1pf(__expf(x));
}

// ---------------------------------------------------------------------------
// Generic f32 GEMM: C[M,N] = A[M,K] @ B[N,K]^T (+bias) (+activation) (+=acc)
// Split output: cols < NS -> C0, cols >= NS -> C1 (for in_proj xm/res split).
// ACT: 0=none, 1=softplus.  ACC: accumulate into C (residual add).
// BM=BN=64, BK=16, 256 threads, 4x4 per-thread tile.
// ---------------------------------------------------------------------------
template<int ACT, bool ACC>
__global__ __launch_bounds__(256)
void gemm_f32(const float* __restrict__ A, int lda,
              const float* __restrict__ Bw,
              const float* __restrict__ bias,
              float* __restrict__ C0, int ldc0,
              float* __restrict__ C1, int ldc1, int NS,
              int M, int N, int K)
{
    __shared__ float As[64][16];   // [m][k], float4-stored
    __shared__ float Bs[16][65];   // [k][n], transposed store, +1 pad

    const int tid = threadIdx.x;
    const int bm = blockIdx.y * 64;
    const int bn = blockIdx.x * 64;
    const int tx = tid & 15;       // n-dir
    const int ty = tid >> 4;       // m-dir

    float acc[4][4] = {};

    const int r  = tid >> 2;        // 0..63
    const int kk = (tid & 3) * 4;   // 0,4,8,12

    for (int k0 = 0; k0 < K; k0 += 16) {
        int ar = bm + r; if (ar >= M) ar = M - 1;
        float4 av = *(const float4*)(A + (size_t)ar * lda + k0 + kk);
        *(float4*)(&As[r][kk]) = av;

        int br = bn + r; if (br >= N) br = N - 1;
        float4 bv = *(const float4*)(Bw + (size_t)br * K + k0 + kk);
        Bs[kk + 0][r] = bv.x;
        Bs[kk + 1][r] = bv.y;
        Bs[kk + 2][r] = bv.z;
        Bs[kk + 3][r] = bv.w;

        __syncthreads();
        #pragma unroll
        for (int k = 0; k < 16; ++k) {
            float a[4], bvv[4];
            #pragma unroll
            for (int i = 0; i < 4; ++i) a[i] = As[ty * 4 + i][k];
            #pragma unroll
            for (int j = 0; j < 4; ++j) bvv[j] = Bs[k][tx * 4 + j];
            #pragma unroll
            for (int i = 0; i < 4; ++i)
                #pragma unroll
                for (int j = 0; j < 4; ++j)
                    acc[i][j] = fmaf(a[i], bvv[j], acc[i][j]);
        }
        __syncthreads();
    }

    #pragma unroll
    for (int i = 0; i < 4; ++i) {
        int m = bm + ty * 4 + i;
        if (m >= M) continue;
        #pragma unroll
        for (int j = 0; j < 4; ++j) {
            int n = bn + tx * 4 + j;
            if (n >= N) continue;
            float v = acc[i][j];
            if (bias) v += bias[n];
            if (ACT == 1) v = softplus_f(v);
            float* dst;
            if (n < NS) dst = C0 + (size_t)m * ldc0 + n;
            else        dst = C1 + (size_t)m * ldc1 + (n - NS);
            if (ACC) *dst += v; else *dst = v;
        }
    }
}

// ---------------------------------------------------------------------------
// RMSNorm: one wave (64 lanes) per token, 4 tokens per block.
// ---------------------------------------------------------------------------
__global__ __launch_bounds__(256)
void rmsnorm_kernel(const float* __restrict__ x, const float* __restrict__ w,
                    float* __restrict__ out)
{
    const int wave = threadIdx.x >> 6;
    const int lane = threadIdx.x & 63;
    const int t = blockIdx.x * 4 + wave;
    const float* xp = x + (size_t)t * DM;
    float4 v = *(const float4*)(xp + lane * 4);
    float ss = v.x * v.x + v.y * v.y + v.z * v.z + v.w * v.w;
    #pragma unroll
    for (int off = 1; off < 64; off <<= 1) ss += __shfl_xor(ss, off);
    float inv = rsqrtf(ss * (1.f / DM) + 1e-5f);
    float4 wv = *(const float4*)(w + lane * 4);
    float4 o;
    o.x = v.x * inv * wv.x;
    o.y = v.y * inv * wv.y;
    o.z = v.z * inv * wv.z;
    o.w = v.w * inv * wv.w;
    *(float4*)(out + (size_t)t * DM + lane * 4) = o;
}

// ---------------------------------------------------------------------------
// Causal depthwise conv (K=4) + SiLU: one thread per (token, channel).
// ---------------------------------------------------------------------------
__global__ __launch_bounds__(256)
void conv_silu_kernel(const float* __restrict__ xm,
                      const float* __restrict__ w,   // [DI][4]
                      const float* __restrict__ cb,  // [DI]
                      float* __restrict__ xs)
{
    const int idx = blockIdx.x * 256 + threadIdx.x;   // over T_TOK*DI
    const int d = idx & (DI - 1);
    const int t = idx >> 9;
    const int l = t & (LL - 1);
    float acc = cb[d];
    const float* wp = w + d * 4;
    #pragma unroll
    for (int k = 0; k < 4; ++k) {
        int ll = l + k - 3;
        if (ll >= 0) acc = fmaf(xm[(size_t)(t + k - 3) * DI + d], wp[k], acc);
    }
    xs[idx] = silu_f(acc);
}

// ---------------------------------------------------------------------------
// Selective scan, sequential over L, fused with +xs*Dp and *silu(res).
// One thread per (b, d) channel; 16 states in registers.
// Writes y in place into xs.
// Grid: 32 blocks (16 b x 2 d-halves), 256 threads.
// ---------------------------------------------------------------------------
__global__ __launch_bounds__(256)
void scan_kernel(const float* __restrict__ delta,  // [T][DI]
                 const float* __restrict__ dbc,    // [T][48]
                 float* __restrict__ xs,           // in: conv out; out: y
                 const float* __restrict__ res,    // [T][DI]
                 const float* __restrict__ A_log,  // [DI][16] (layer slice)
                 const float* __restrict__ Dp)     // [DI]
{
    __shared__ float bc[16][32];  // per step: B[0..15], C[16..31]

    const int b = blockIdx.x >> 1;
    const int d = ((blockIdx.x & 1) << 8) + threadIdx.x;

    float An[16];
    #pragma unroll
    for (int n = 0; n < 16; ++n) An[n] = -__expf(A_log[d * 16 + n]);
    const float Dv = Dp[d];

    float h[16];
    #pragma unroll
    for (int n = 0; n < 16; ++n) h[n] = 0.f;

    const int base_t = b << 10;

    for (int tile = 0; tile < LL / 16; ++tile) {
        __syncthreads();
        {
            int i = threadIdx.x;
            int s = i >> 5, c = i & 31;
            bc[s][c]     = dbc[(size_t)(base_t + tile * 16 + s) * 48 + 16 + c];
            bc[s + 8][c] = dbc[(size_t)(base_t + tile * 16 + s + 8) * 48 + 16 + c];
        }
        __syncthreads();

        #pragma unroll
        for (int s = 0; s < 16; ++s) {
            const size_t t = (size_t)(base_t + tile * 16 + s);
            const size_t off = t * DI + d;
            const float dl = delta[off];
            const float xv = xs[off];
            const float rv = res[off];
            const float du = dl * xv;
            float acc = 0.f;
            #pragma unroll
            for (int n = 0; n < 16; ++n) {
                float a = __expf(dl * An[n]);
                h[n] = fmaf(a, h[n], du * bc[s][n]);
                acc  = fmaf(h[n], bc[s][16 + n], acc);
            }
            float y = fmaf(xv, Dv, acc);
            xs[off] = y * silu_f(rv);
        }
    }
}

// ---------------------------------------------------------------------------
// Final head helpers
// ---------------------------------------------------------------------------
__global__ void zero_kernel(float* __restrict__ p, int n)
{
    int i = blockIdx.x * 256 + threadIdx.x;
    if (i < n) p[i] = 0.f;
}

__global__ __launch_bounds__(256)
void hmean_kernel(const float* __restrict__ hn, float* __restrict__ hmean)
{
    // grid: 16 b x 16 l-chunks; block: 256 threads (one per d)
    const int b = blockIdx.x >> 4;
    const int lc = blockIdx.x & 15;
    const int d = threadIdx.x;
    float s = 0.f;
    for (int l = lc * 64; l < lc * 64 + 64; ++l)
        s += hn[((size_t)(b * LL + l)) * DM + d];
    atomicAdd(&hmean[b * DM + d], s * (1.f / LL));
}

__global__ __launch_bounds__(256)
void mlp_kernel(const float* __restrict__ feat, const float* __restrict__ W1,
                const float* __restrict__ b1, const float* __restrict__ W2,
                const float* __restrict__ b2, float* __restrict__ out)
{
    __shared__ float hid[BB][MID + 2];
    const int tid = threadIdx.x;
    for (int idx = tid; idx < BB * MID; idx += 256) {
        int b = idx / MID, m = idx % MID;
        float s = b1[m];
        for (int k = 0; k < OUT_DIM; ++k)
            s = fmaf(feat[b * OUT_DIM + k], W1[m * OUT_DIM + k], s);
        hid[b][m] = fmaxf(s, 0.f);
    }
    __syncthreads();
    if (tid < BB * NCLS) {
        int b = tid / NCLS, c = tid % NCLS;
        float s = b2[c];
        for (int k = 0; k < MID; ++k)
            s = fmaf(hid[b][k], W2[c * MID + k], s);
        out[b * NCLS + c] = s;
    }
}

// ---------------------------------------------------------------------------
extern "C" void kernel_launch(void* const* d_in, const int* in_sizes, int n_in,
                              void* d_out, int out_size, void* d_ws, size_t ws_size,
                              hipStream_t stream)
{
    const float* x       = (const float*)d_in[0];
    const float* emb_W   = (const float*)d_in[1];
    const float* emb_b   = (const float*)d_in[2];
    const float* in_W    = (const float*)d_in[3];
    const float* conv_W  = (const float*)d_in[4];
    const float* conv_b  = (const float*)d_in[5];
    const float* xp_W    = (const float*)d_in[6];
    const float* dt_W    = (const float*)d_in[7];
    const float* dt_b    = (const float*)d_in[8];
    const float* A_log   = (const float*)d_in[9];
    const float* Dp      = (const float*)d_in[10];
    const float* out_W   = (const float*)d_in[11];
    const float* norm_W  = (const float*)d_in[12];
    const float* normf_W = (const float*)d_in[13];
    const float* head_W  = (const float*)d_in[14];
    const float* head_b  = (const float*)d_in[15];
    const float* W1      = (const float*)d_in[16];
    const float* b1      = (const float*)d_in[17];
    const float* W2      = (const float*)d_in[18];
    const float* b2      = (const float*)d_in[19];

    float* ws    = (float*)d_ws;
    float* h     = ws;                              // T*256
    float* hn    = h   + (size_t)T_TOK * DM;        // T*256
    float* xm    = hn  + (size_t)T_TOK * DM;        // T*512 (also reused as delta)
    float* res   = xm  + (size_t)T_TOK * DI;        // T*512
    float* xs    = res + (size_t)T_TOK * DI;        // T*512
    float* dbc   = xs  + (size_t)T_TOK * DI;        // T*48
    float* hmean = dbc + (size_t)T_TOK * 48;        // 16*256
    float* feat  = hmean + BB * DM;                 // 16*128
    float* delta = xm;  // alias: xm dead after conv, delta written after

    dim3 blk(256);

    // Embed: h = x @ emb_W^T + emb_b   [T,256] = [T,64]x[256,64]^T
    gemm_f32<0, false><<<dim3(DM / 64, T_TOK / 64), blk, 0, stream>>>(
        x, IN_FEAT, emb_W, emb_b, h, DM, h, DM, DM, T_TOK, DM, IN_FEAT);

    for (int i = 0; i < NL; ++i) {
        // hn = rmsnorm(h, norm_W[i])
        rmsnorm_kernel<<<T_TOK / 4, blk, 0, stream>>>(h, norm_W + i * DM, hn);

        // xr = hn @ in_W[i]^T  -> split xm | res
        gemm_f32<0, false><<<dim3(2 * DI / 64, T_TOK / 64), blk, 0, stream>>>(
            hn, DM, in_W + (size_t)i * 2 * DI * DM, nullptr,
            xm, DI, res, DI, DI, T_TOK, 2 * DI, DM);

        // xs = silu(causal_dwconv(xm))
        conv_silu_kernel<<<(T_TOK * DI) / 256, blk, 0, stream>>>(
            xm, conv_W + (size_t)i * DI * DCONV, conv_b + i * DI, xs);

        // dbc = xs @ xp_W[i]^T   [T,48]
        gemm_f32<0, false><<<dim3(1, T_TOK / 64), blk, 0, stream>>>(
            xs, DI, xp_W + (size_t)i * 48 * DI, nullptr,
            dbc, 48, dbc, 48, 48, T_TOK, 48, DI);

        // delta = softplus(dlt @ dt_W[i]^T + dt_b[i])   (dlt = dbc[:, :16], lda=48)
        gemm_f32<1, false><<<dim3(DI / 64, T_TOK / 64), blk, 0, stream>>>(
            dbc, 48, dt_W + (size_t)i * DI * DTRANK, dt_b + i * DI,
            delta, DI, delta, DI, DI, T_TOK, DI, DTRANK);

        // selective scan + gating, y written in place into xs
        scan_kernel<<<32, blk, 0, stream>>>(
            delta, dbc, xs, res, A_log + (size_t)i * DI * DSTATE, Dp + i * DI);

        // h += y @ out_W[i]^T
        gemm_f32<0, true><<<dim3(DM / 64, T_TOK / 64), blk, 0, stream>>>(
            xs, DI, out_W + (size_t)i * DM * DI, nullptr,
            h, DM, h, DM, DM, T_TOK, DM, DI);
    }

    // Final norm + head (mean over L commutes with linear head)
    rmsnorm_kernel<<<T_TOK / 4, blk, 0, stream>>>(h, normf_W, hn);
    zero_kernel<<<(BB * DM + 255) / 256, blk, 0, stream>>>(hmean, BB * DM);
    hmean_kernel<<<256, blk, 0, stream>>>(hn, hmean);
    gemm_f32<0, false><<<dim3(2, 1), blk, 0, stream>>>(
        hmean, DM, head_W, head_b, feat, OUT_DIM, feat, OUT_DIM, OUT_DIM,
        BB, OUT_DIM, DM);
    mlp_kernel<<<1, blk, 0, stream>>>(feat, W1, b1, W2, b2, (float*)d_out);
}

// Round 2
// 2063.123 us; speedup vs baseline: 2.1474x; 2.1474x over previous
//
#include <hip/hip_runtime.h>
#include <math.h>

// Problem constants
#define NL 4
#define DM 256
#define DI 512
#define DSTATE 16
#define DTRANK 16
#define DCONV 4
#define IN_FEAT 64
#define OUT_DIM 128
#define MID 50
#define NCLS 3
#define BB 16
#define LL 1024
#define T_TOK (BB*LL)   // 16384
#define CHUNK 64
#define NCH (LL/CHUNK)  // 16

__device__ __forceinline__ float silu_f(float x) {
    return x / (1.f + __expf(-x));
}
__device__ __forceinline__ float softplus_f(float x) {
    return (x > 20.f) ? x : log1pf(__expf(x));
}

// ---------------------------------------------------------------------------
// Generic f32 GEMM: C[M,N] = A[M,K] @ B[N,K]^T (+bias) (+activation) (+=acc)
// Split output: cols < NS -> C0, cols >= NS -> C1 (for in_proj xm/res split).
// ACT: 0=none, 1=softplus.  ACC: accumulate into C (residual add).
// BM=BN=64, BK=16, 256 threads, 4x4 per-thread tile.
// ---------------------------------------------------------------------------
template<int ACT, bool ACC>
__global__ __launch_bounds__(256)
void gemm_f32(const float* __restrict__ A, int lda,
              const float* __restrict__ Bw,
              const float* __restrict__ bias,
              float* __restrict__ C0, int ldc0,
              float* __restrict__ C1, int ldc1, int NS,
              int M, int N, int K)
{
    __shared__ float As[64][16];   // [m][k], float4-stored
    __shared__ float Bs[16][65];   // [k][n], transposed store, +1 pad

    const int tid = threadIdx.x;
    const int bm = blockIdx.y * 64;
    const int bn = blockIdx.x * 64;
    const int tx = tid & 15;       // n-dir
    const int ty = tid >> 4;       // m-dir

    float acc[4][4] = {};

    const int r  = tid >> 2;        // 0..63
    const int kk = (tid & 3) * 4;   // 0,4,8,12

    for (int k0 = 0; k0 < K; k0 += 16) {
        int ar = bm + r; if (ar >= M) ar = M - 1;
        float4 av = *(const float4*)(A + (size_t)ar * lda + k0 + kk);
        *(float4*)(&As[r][kk]) = av;

        int br = bn + r; if (br >= N) br = N - 1;
        float4 bv = *(const float4*)(Bw + (size_t)br * K + k0 + kk);
        Bs[kk + 0][r] = bv.x;
        Bs[kk + 1][r] = bv.y;
        Bs[kk + 2][r] = bv.z;
        Bs[kk + 3][r] = bv.w;

        __syncthreads();
        #pragma unroll
        for (int k = 0; k < 16; ++k) {
            float a[4], bvv[4];
            #pragma unroll
            for (int i = 0; i < 4; ++i) a[i] = As[ty * 4 + i][k];
            #pragma unroll
            for (int j = 0; j < 4; ++j) bvv[j] = Bs[k][tx * 4 + j];
            #pragma unroll
            for (int i = 0; i < 4; ++i)
                #pragma unroll
                for (int j = 0; j < 4; ++j)
                    acc[i][j] = fmaf(a[i], bvv[j], acc[i][j]);
        }
        __syncthreads();
    }

    #pragma unroll
    for (int i = 0; i < 4; ++i) {
        int m = bm + ty * 4 + i;
        if (m >= M) continue;
        #pragma unroll
        for (int j = 0; j < 4; ++j) {
            int n = bn + tx * 4 + j;
            if (n >= N) continue;
            float v = acc[i][j];
            if (bias) v += bias[n];
            if (ACT == 1) v = softplus_f(v);
            float* dst;
            if (n < NS) dst = C0 + (size_t)m * ldc0 + n;
            else        dst = C1 + (size_t)m * ldc1 + (n - NS);
            if (ACC) *dst += v; else *dst = v;
        }
    }
}

// ---------------------------------------------------------------------------
// RMSNorm: one wave (64 lanes) per token, 4 tokens per block.
// ---------------------------------------------------------------------------
__global__ __launch_bounds__(256)
void rmsnorm_kernel(const float* __restrict__ x, const float* __restrict__ w,
                    float* __restrict__ out)
{
    const int wave = threadIdx.x >> 6;
    const int lane = threadIdx.x & 63;
    const int t = blockIdx.x * 4 + wave;
    const float* xp = x + (size_t)t * DM;
    float4 v = *(const float4*)(xp + lane * 4);
    float ss = v.x * v.x + v.y * v.y + v.z * v.z + v.w * v.w;
    #pragma unroll
    for (int off = 1; off < 64; off <<= 1) ss += __shfl_xor(ss, off);
    float inv = rsqrtf(ss * (1.f / DM) + 1e-5f);
    float4 wv = *(const float4*)(w + lane * 4);
    float4 o;
    o.x = v.x * inv * wv.x;
    o.y = v.y * inv * wv.y;
    o.z = v.z * inv * wv.z;
    o.w = v.w * inv * wv.w;
    *(float4*)(out + (size_t)t * DM + lane * 4) = o;
}

// ---------------------------------------------------------------------------
// Causal depthwise conv (K=4) + SiLU: one thread per (token, channel).
// ---------------------------------------------------------------------------
__global__ __launch_bounds__(256)
void conv_silu_kernel(const float* __restrict__ xm,
                      const float* __restrict__ w,   // [DI][4]
                      const float* __restrict__ cb,  // [DI]
                      float* __restrict__ xs)
{
    const int idx = blockIdx.x * 256 + threadIdx.x;   // over T_TOK*DI
    const int d = idx & (DI - 1);
    const int t = idx >> 9;
    const int l = t & (LL - 1);
    float acc = cb[d];
    const float* wp = w + d * 4;
    #pragma unroll
    for (int k = 0; k < 4; ++k) {
        int ll = l + k - 3;
        if (ll >= 0) acc = fmaf(xm[(size_t)(t + k - 3) * DI + d], wp[k], acc);
    }
    xs[idx] = silu_f(acc);
}

// ---------------------------------------------------------------------------
// Chunked parallel selective scan.
// p1: per (b,chunk,d) local scan from h=0 -> final local state + sum(delta)
// p2: sequential combine over chunks (tiny); rewrites st with INITIAL states
// p3: re-scan with correct initial state, fused C-dot + Dp + silu(res) gate
// st layout: [((b*NCH+c)*DSTATE+n)*DI + d]  (coalesced in d)
// ---------------------------------------------------------------------------
__global__ __launch_bounds__(256)
void scan_p1(const float* __restrict__ delta,  // [T][DI]
             const float* __restrict__ dbc,    // [T][48]
             const float* __restrict__ xs,     // [T][DI]
             const float* __restrict__ A_log,  // [DI][16]
             float* __restrict__ st,           // [B][NCH][16][DI]
             float* __restrict__ sdl)          // [B][NCH][DI]
{
    const int blk = blockIdx.x;          // 0..511
    const int dhalf = blk & 1;
    const int chunk = (blk >> 1) & (NCH - 1);
    const int b = blk >> 5;
    const int d = (dhalf << 8) + threadIdx.x;
    const int t0 = b * LL + chunk * CHUNK;

    __shared__ float Bs[CHUNK][DSTATE];
    for (int i = threadIdx.x; i < CHUNK * DSTATE; i += 256) {
        int s = i >> 4, n = i & 15;
        Bs[s][n] = dbc[(size_t)(t0 + s) * 48 + 16 + n];
    }
    __syncthreads();

    float An[16];
    #pragma unroll
    for (int n = 0; n < 16; ++n) An[n] = -__expf(A_log[d * 16 + n]);

    float h[16];
    #pragma unroll
    for (int n = 0; n < 16; ++n) h[n] = 0.f;
    float sumdl = 0.f;

    for (int s = 0; s < CHUNK; ++s) {
        const size_t off = (size_t)(t0 + s) * DI + d;
        const float dl = delta[off];
        const float du = dl * xs[off];
        sumdl += dl;
        #pragma unroll
        for (int n = 0; n < 16; ++n) {
            float a = __expf(dl * An[n]);
            h[n] = fmaf(a, h[n], du * Bs[s][n]);
        }
    }

    const size_t base = ((size_t)(b * NCH + chunk) * DSTATE) * DI + d;
    #pragma unroll
    for (int n = 0; n < 16; ++n) st[base + (size_t)n * DI] = h[n];
    sdl[(size_t)(b * NCH + chunk) * DI + d] = sumdl;
}

__global__ __launch_bounds__(256)
void scan_p2(float* __restrict__ st, const float* __restrict__ sdl,
             const float* __restrict__ A_log)
{
    const int b = blockIdx.x >> 1;
    const int d = ((blockIdx.x & 1) << 8) + threadIdx.x;

    float An[16];
    #pragma unroll
    for (int n = 0; n < 16; ++n) An[n] = -__expf(A_log[d * 16 + n]);

    float H[16];
    #pragma unroll
    for (int n = 0; n < 16; ++n) H[n] = 0.f;

    for (int c = 0; c < NCH; ++c) {
        const size_t base = ((size_t)(b * NCH + c) * DSTATE) * DI + d;
        const float sums = sdl[(size_t)(b * NCH + c) * DI + d];
        #pragma unroll
        for (int n = 0; n < 16; ++n) {
            float fin = st[base + (size_t)n * DI];
            float dec = __expf(An[n] * sums);
            st[base + (size_t)n * DI] = H[n];   // initial state for chunk c
            H[n] = fmaf(dec, H[n], fin);
        }
    }
}

__global__ __launch_bounds__(256)
void scan_p3(const float* __restrict__ delta,
             const float* __restrict__ dbc,
             float* __restrict__ xs,            // in: conv out; out: y*gate
             const float* __restrict__ res,
             const float* __restrict__ A_log,
             const float* __restrict__ Dp,
             const float* __restrict__ st)      // initial states
{
    const int blk = blockIdx.x;
    const int dhalf = blk & 1;
    const int chunk = (blk >> 1) & (NCH - 1);
    const int b = blk >> 5;
    const int d = (dhalf << 8) + threadIdx.x;
    const int t0 = b * LL + chunk * CHUNK;

    __shared__ float BCs[CHUNK][32];   // B[0..15], C[16..31]
    for (int i = threadIdx.x; i < CHUNK * 32; i += 256) {
        int s = i >> 5, c = i & 31;
        BCs[s][c] = dbc[(size_t)(t0 + s) * 48 + 16 + c];
    }
    __syncthreads();

    float An[16];
    #pragma unroll
    for (int n = 0; n < 16; ++n) An[n] = -__expf(A_log[d * 16 + n]);
    const float Dv = Dp[d];

    const size_t base = ((size_t)(b * NCH + chunk) * DSTATE) * DI + d;
    float h[16];
    #pragma unroll
    for (int n = 0; n < 16; ++n) h[n] = st[base + (size_t)n * DI];

    for (int s = 0; s < CHUNK; ++s) {
        const size_t off = (size_t)(t0 + s) * DI + d;
        const float dl = delta[off];
        const float xv = xs[off];
        const float rv = res[off];
        const float du = dl * xv;
        float acc = 0.f;
        #pragma unroll
        for (int n = 0; n < 16; ++n) {
            float a = __expf(dl * An[n]);
            h[n] = fmaf(a, h[n], du * BCs[s][n]);
            acc  = fmaf(h[n], BCs[s][16 + n], acc);
        }
        float y = fmaf(xv, Dv, acc);
        xs[off] = y * silu_f(rv);
    }
}

// ---------------------------------------------------------------------------
// Final head helpers
// ---------------------------------------------------------------------------
__global__ void zero_kernel(float* __restrict__ p, int n)
{
    int i = blockIdx.x * 256 + threadIdx.x;
    if (i < n) p[i] = 0.f;
}

__global__ __launch_bounds__(256)
void hmean_kernel(const float* __restrict__ hn, float* __restrict__ hmean)
{
    // grid: 16 b x 16 l-chunks; block: 256 threads (one per d)
    const int b = blockIdx.x >> 4;
    const int lc = blockIdx.x & 15;
    const int d = threadIdx.x;
    float s = 0.f;
    for (int l = lc * 64; l < lc * 64 + 64; ++l)
        s += hn[((size_t)(b * LL + l)) * DM + d];
    atomicAdd(&hmean[b * DM + d], s * (1.f / LL));
}

__global__ __launch_bounds__(256)
void mlp_kernel(const float* __restrict__ feat, const float* __restrict__ W1,
                const float* __restrict__ b1, const float* __restrict__ W2,
                const float* __restrict__ b2, float* __restrict__ out)
{
    __shared__ float hid[BB][MID + 2];
    const int tid = threadIdx.x;
    for (int idx = tid; idx < BB * MID; idx += 256) {
        int b = idx / MID, m = idx % MID;
        float s = b1[m];
        for (int k = 0; k < OUT_DIM; ++k)
            s = fmaf(feat[b * OUT_DIM + k], W1[m * OUT_DIM + k], s);
        hid[b][m] = fmaxf(s, 0.f);
    }
    __syncthreads();
    if (tid < BB * NCLS) {
        int b = tid / NCLS, c = tid % NCLS;
        float s = b2[c];
        for (int k = 0; k < MID; ++k)
            s = fmaf(hid[b][k], W2[c * MID + k], s);
        out[b * NCLS + c] = s;
    }
}

// ---------------------------------------------------------------------------
extern "C" void kernel_launch(void* const* d_in, const int* in_sizes, int n_in,
                              void* d_out, int out_size, void* d_ws, size_t ws_size,
                              hipStream_t stream)
{
    const float* x       = (const float*)d_in[0];
    const float* emb_W   = (const float*)d_in[1];
    const float* emb_b   = (const float*)d_in[2];
    const float* in_W    = (const float*)d_in[3];
    const float* conv_W  = (const float*)d_in[4];
    const float* conv_b  = (const float*)d_in[5];
    const float* xp_W    = (const float*)d_in[6];
    const float* dt_W    = (const float*)d_in[7];
    const float* dt_b    = (const float*)d_in[8];
    const float* A_log   = (const float*)d_in[9];
    const float* Dp      = (const float*)d_in[10];
    const float* out_W   = (const float*)d_in[11];
    const float* norm_W  = (const float*)d_in[12];
    const float* normf_W = (const float*)d_in[13];
    const float* head_W  = (const float*)d_in[14];
    const float* head_b  = (const float*)d_in[15];
    const float* W1      = (const float*)d_in[16];
    const float* b1      = (const float*)d_in[17];
    const float* W2      = (const float*)d_in[18];
    const float* b2      = (const float*)d_in[19];

    float* ws    = (float*)d_ws;
    float* h     = ws;                              // T*256
    float* hn    = h   + (size_t)T_TOK * DM;        // T*256
    float* xm    = hn  + (size_t)T_TOK * DM;        // T*512 (also reused as delta)
    float* res   = xm  + (size_t)T_TOK * DI;        // T*512
    float* xs    = res + (size_t)T_TOK * DI;        // T*512
    float* dbc   = xs  + (size_t)T_TOK * DI;        // T*48
    float* hmean = dbc + (size_t)T_TOK * 48;        // 16*256
    float* feat  = hmean + BB * DM;                 // 16*128
    float* delta = xm;  // alias: xm dead after conv, delta written after
    // scan state buffers alias hn (dead between in_proj and next rmsnorm):
    // st: B*NCH*16*DI = 2.10M floats, sdl: B*NCH*DI = 0.13M; hn holds 4.19M.
    float* st  = hn;
    float* sdl = hn + (size_t)BB * NCH * DSTATE * DI;

    dim3 blk(256);

    // Embed: h = x @ emb_W^T + emb_b   [T,256] = [T,64]x[256,64]^T
    gemm_f32<0, false><<<dim3(DM / 64, T_TOK / 64), blk, 0, stream>>>(
        x, IN_FEAT, emb_W, emb_b, h, DM, h, DM, DM, T_TOK, DM, IN_FEAT);

    for (int i = 0; i < NL; ++i) {
        // hn = rmsnorm(h, norm_W[i])
        rmsnorm_kernel<<<T_TOK / 4, blk, 0, stream>>>(h, norm_W + i * DM, hn);

        // xr = hn @ in_W[i]^T  -> split xm | res
        gemm_f32<0, false><<<dim3(2 * DI / 64, T_TOK / 64), blk, 0, stream>>>(
            hn, DM, in_W + (size_t)i * 2 * DI * DM, nullptr,
            xm, DI, res, DI, DI, T_TOK, 2 * DI, DM);

        // xs = silu(causal_dwconv(xm))
        conv_silu_kernel<<<(T_TOK * DI) / 256, blk, 0, stream>>>(
            xm, conv_W + (size_t)i * DI * DCONV, conv_b + i * DI, xs);

        // dbc = xs @ xp_W[i]^T   [T,48]
        gemm_f32<0, false><<<dim3(1, T_TOK / 64), blk, 0, stream>>>(
            xs, DI, xp_W + (size_t)i * 48 * DI, nullptr,
            dbc, 48, dbc, 48, 48, T_TOK, 48, DI);

        // delta = softplus(dlt @ dt_W[i]^T + dt_b[i])   (dlt = dbc[:, :16], lda=48)
        gemm_f32<1, false><<<dim3(DI / 64, T_TOK / 64), blk, 0, stream>>>(
            dbc, 48, dt_W + (size_t)i * DI * DTRANK, dt_b + i * DI,
            delta, DI, delta, DI, DI, T_TOK, DI, DTRANK);

        // chunked parallel selective scan (+ gating), y in place into xs
        const float* Al = A_log + (size_t)i * DI * DSTATE;
        scan_p1<<<BB * NCH * 2, blk, 0, stream>>>(delta, dbc, xs, Al, st, sdl);
        scan_p2<<<32, blk, 0, stream>>>(st, sdl, Al);
        scan_p3<<<BB * NCH * 2, blk, 0, stream>>>(delta, dbc, xs, res, Al,
                                                  Dp + i * DI, st);

        // h += y @ out_W[i]^T
        gemm_f32<0, true><<<dim3(DM / 64, T_TOK / 64), blk, 0, stream>>>(
            xs, DI, out_W + (size_t)i * DM * DI, nullptr,
            h, DM, h, DM, DM, T_TOK, DM, DI);
    }

    // Final norm + head (mean over L commutes with linear head)
    rmsnorm_kernel<<<T_TOK / 4, blk, 0, stream>>>(h, normf_W, hn);
    zero_kernel<<<(BB * DM + 255) / 256, blk, 0, stream>>>(hmean, BB * DM);
    hmean_kernel<<<256, blk, 0, stream>>>(hn, hmean);
    gemm_f32<0, false><<<dim3(2, 1), blk, 0, stream>>>(
        hmean, DM, head_W, head_b, feat, OUT_DIM, feat, OUT_DIM, OUT_DIM,
        BB, OUT_DIM, DM);
    mlp_kernel<<<1, blk, 0, stream>>>(feat, W1, b1, W2, b2, (float*)d_out);
}

// Round 3
// 1298.133 us; speedup vs baseline: 3.4129x; 1.5893x over previous
//
#include <hip/hip_runtime.h>
#include <math.h>

// Problem constants
#define NL 4
#define DM 256
#define DI 512
#define DSTATE 16
#define DTRANK 16
#define DCONV 4
#define IN_FEAT 64
#define OUT_DIM 128
#define MID 50
#define NCLS 3
#define BB 16
#define LL 1024
#define T_TOK (BB*LL)   // 16384
#define CHUNK 64
#define NCH (LL/CHUNK)  // 16

typedef short bf8_t __attribute__((ext_vector_type(8)));   // 8 bf16 (4 VGPRs)
typedef float f32x4 __attribute__((ext_vector_type(4)));

__device__ __forceinline__ float silu_f(float x) {
    return x / (1.f + __expf(-x));
}
__device__ __forceinline__ float softplus_f(float x) {
    return (x > 20.f) ? x : log1pf(__expf(x));
}
__device__ __forceinline__ unsigned short f2bf_rne(float f) {
    unsigned int u = __float_as_uint(f);
    unsigned int r = (u + 0x7FFFu + ((u >> 16) & 1u)) >> 16;
    return (unsigned short)r;
}
__device__ __forceinline__ float bf2f(unsigned short s) {
    return __uint_as_float(((unsigned int)s) << 16);
}
__device__ __forceinline__ void split_bf(float v, unsigned short& hi, unsigned short& lo) {
    unsigned short h = f2bf_rne(v);
    hi = h;
    lo = f2bf_rne(v - bf2f(h));
}

// ---------------------------------------------------------------------------
// bf16x3 MFMA GEMM: C[M,N] = A[M,K] @ W[N,K]^T with near-f32 accuracy.
// A planes Ahi/Alo [M][K] bf16; W planes Whi/Wlo [N][K] bf16.
// acc += Ah*Wh + Ah*Wl + Al*Wh  (dropped Al*Wl ~ 2^-18 relative)
// BM=BN=128, BK=32, 256 threads = 4 waves, wave tile 64x64 (4x4 16x16 frags).
// M,N multiples of 128; K multiple of 32 (or ==64). No bounds checks.
// ---------------------------------------------------------------------------
template<bool ACC, bool BIAS, bool SPLIT>
__global__ __launch_bounds__(256, 2)
void gemm_bf16x3(const unsigned short* __restrict__ Ahi,
                 const unsigned short* __restrict__ Alo,
                 const unsigned short* __restrict__ Whi,
                 const unsigned short* __restrict__ Wlo,
                 const float* __restrict__ bias,
                 float* __restrict__ C0, int ldc0,
                 float* __restrict__ C1, int ldc1, int NS,
                 int M, int N, int K)
{
    // 4 planes: 0=Ahi 1=Alo 2=Whi 3=Wlo. Row stride 40 bf16 (pad = +1 16B unit).
    __shared__ __align__(16) unsigned short lds[4][128][40];

    const int tid = threadIdx.x;
    const int lane = tid & 63;
    const int wid = tid >> 6;
    const int wr = wid >> 1;          // wave row (0..1)
    const int wc = wid & 1;           // wave col (0..1)
    const int bm = blockIdx.y * 128;
    const int bn = blockIdx.x * 128;

    f32x4 acc[4][4];
    #pragma unroll
    for (int i = 0; i < 4; ++i)
        #pragma unroll
        for (int j = 0; j < 4; ++j)
            acc[i][j] = (f32x4){0.f, 0.f, 0.f, 0.f};

    const int l15 = lane & 15;
    const int kc  = lane >> 4;        // 0..3, k-offset = kc*8

    for (int k0 = 0; k0 < K; k0 += 32) {
        __syncthreads();
        #pragma unroll
        for (int pass = 0; pass < 2; ++pass) {
            const int uu = tid + pass * 256;     // 0..511
            const int row = uu >> 2;
            const int c = uu & 3;
            const size_t ga = (size_t)(bm + row) * K + k0 + c * 8;
            const size_t gb = (size_t)(bn + row) * K + k0 + c * 8;
            *(bf8_t*)&lds[0][row][c * 8] = *(const bf8_t*)(Ahi + ga);
            *(bf8_t*)&lds[1][row][c * 8] = *(const bf8_t*)(Alo + ga);
            *(bf8_t*)&lds[2][row][c * 8] = *(const bf8_t*)(Whi + gb);
            *(bf8_t*)&lds[3][row][c * 8] = *(const bf8_t*)(Wlo + gb);
        }
        __syncthreads();

        bf8_t ah[4], al[4], bh[4], bl[4];
        #pragma unroll
        for (int mi = 0; mi < 4; ++mi) {
            const int r = wr * 64 + mi * 16 + l15;
            ah[mi] = *(bf8_t*)&lds[0][r][kc * 8];
            al[mi] = *(bf8_t*)&lds[1][r][kc * 8];
        }
        #pragma unroll
        for (int nj = 0; nj < 4; ++nj) {
            const int r = wc * 64 + nj * 16 + l15;
            bh[nj] = *(bf8_t*)&lds[2][r][kc * 8];
            bl[nj] = *(bf8_t*)&lds[3][r][kc * 8];
        }

        #pragma unroll
        for (int mi = 0; mi < 4; ++mi)
            #pragma unroll
            for (int nj = 0; nj < 4; ++nj) {
                acc[mi][nj] = __builtin_amdgcn_mfma_f32_16x16x32_bf16(
                    ah[mi], bh[nj], acc[mi][nj], 0, 0, 0);
                acc[mi][nj] = __builtin_amdgcn_mfma_f32_16x16x32_bf16(
                    ah[mi], bl[nj], acc[mi][nj], 0, 0, 0);
                acc[mi][nj] = __builtin_amdgcn_mfma_f32_16x16x32_bf16(
                    al[mi], bh[nj], acc[mi][nj], 0, 0, 0);
            }
    }

    // Epilogue: C/D layout col = lane&15, row = (lane>>4)*4 + reg
    #pragma unroll
    for (int mi = 0; mi < 4; ++mi) {
        const int row0 = bm + wr * 64 + mi * 16 + (lane >> 4) * 4;
        #pragma unroll
        for (int nj = 0; nj < 4; ++nj) {
            const int col = bn + wc * 64 + nj * 16 + l15;
            float bv = BIAS ? bias[col] : 0.f;
            #pragma unroll
            for (int r = 0; r < 4; ++r) {
                float val = acc[mi][nj][r] + bv;
                const int m = row0 + r;
                float* dst;
                if (SPLIT && col >= NS) dst = C1 + (size_t)m * ldc1 + (col - NS);
                else                    dst = C0 + (size_t)m * ldc0 + col;
                if (ACC) *dst += val; else *dst = val;
            }
        }
    }
}

// ---------------------------------------------------------------------------
// f32 GEMM (kept for small/odd shapes): C[M,N] = A[M,K] @ B[N,K]^T
// ---------------------------------------------------------------------------
template<int ACT, bool ACC>
__global__ __launch_bounds__(256)
void gemm_f32(const float* __restrict__ A, int lda,
              const float* __restrict__ Bw,
              const float* __restrict__ bias,
              float* __restrict__ C0, int ldc0,
              float* __restrict__ C1, int ldc1, int NS,
              int M, int N, int K)
{
    __shared__ float As[64][16];
    __shared__ float Bs[16][65];

    const int tid = threadIdx.x;
    const int bm = blockIdx.y * 64;
    const int bn = blockIdx.x * 64;
    const int tx = tid & 15;
    const int ty = tid >> 4;

    float acc[4][4] = {};

    const int r  = tid >> 2;
    const int kk = (tid & 3) * 4;

    for (int k0 = 0; k0 < K; k0 += 16) {
        int ar = bm + r; if (ar >= M) ar = M - 1;
        float4 av = *(const float4*)(A + (size_t)ar * lda + k0 + kk);
        *(float4*)(&As[r][kk]) = av;

        int br = bn + r; if (br >= N) br = N - 1;
        float4 bv = *(const float4*)(Bw + (size_t)br * K + k0 + kk);
        Bs[kk + 0][r] = bv.x;
        Bs[kk + 1][r] = bv.y;
        Bs[kk + 2][r] = bv.z;
        Bs[kk + 3][r] = bv.w;

        __syncthreads();
        #pragma unroll
        for (int k = 0; k < 16; ++k) {
            float a[4], bvv[4];
            #pragma unroll
            for (int i = 0; i < 4; ++i) a[i] = As[ty * 4 + i][k];
            #pragma unroll
            for (int j = 0; j < 4; ++j) bvv[j] = Bs[k][tx * 4 + j];
            #pragma unroll
            for (int i = 0; i < 4; ++i)
                #pragma unroll
                for (int j = 0; j < 4; ++j)
                    acc[i][j] = fmaf(a[i], bvv[j], acc[i][j]);
        }
        __syncthreads();
    }

    #pragma unroll
    for (int i = 0; i < 4; ++i) {
        int m = bm + ty * 4 + i;
        if (m >= M) continue;
        #pragma unroll
        for (int j = 0; j < 4; ++j) {
            int n = bn + tx * 4 + j;
            if (n >= N) continue;
            float v = acc[i][j];
            if (bias) v += bias[n];
            if (ACT == 1) v = softplus_f(v);
            float* dst;
            if (n < NS) dst = C0 + (size_t)m * ldc0 + n;
            else        dst = C1 + (size_t)m * ldc1 + (n - NS);
            if (ACC) *dst += v; else *dst = v;
        }
    }
}

// ---------------------------------------------------------------------------
// Split f32 -> (hi, lo) bf16 planes, vectorized by 4.
// ---------------------------------------------------------------------------
__global__ __launch_bounds__(256)
void split4_kernel(const float* __restrict__ src, unsigned short* __restrict__ hi,
                   unsigned short* __restrict__ lo, int n4)
{
    int i = blockIdx.x * 256 + threadIdx.x;
    if (i >= n4) return;
    float4 v = ((const float4*)src)[i];
    ushort4 h, l;
    split_bf(v.x, h.x, l.x);
    split_bf(v.y, h.y, l.y);
    split_bf(v.z, h.z, l.z);
    split_bf(v.w, h.w, l.w);
    ((ushort4*)hi)[i] = h;
    ((ushort4*)lo)[i] = l;
}

// ---------------------------------------------------------------------------
// RMSNorm -> bf16 hi/lo planes. One wave per token, 4 tokens/block.
// ---------------------------------------------------------------------------
__global__ __launch_bounds__(256)
void rmsnorm_bf16_kernel(const float* __restrict__ x, const float* __restrict__ w,
                         unsigned short* __restrict__ hi, unsigned short* __restrict__ lo)
{
    const int wave = threadIdx.x >> 6;
    const int lane = threadIdx.x & 63;
    const int t = blockIdx.x * 4 + wave;
    const float* xp = x + (size_t)t * DM;
    float4 v = *(const float4*)(xp + lane * 4);
    float ss = v.x * v.x + v.y * v.y + v.z * v.z + v.w * v.w;
    #pragma unroll
    for (int off = 1; off < 64; off <<= 1) ss += __shfl_xor(ss, off);
    float inv = rsqrtf(ss * (1.f / DM) + 1e-5f);
    float4 wv = *(const float4*)(w + lane * 4);
    float o[4] = { v.x * inv * wv.x, v.y * inv * wv.y,
                   v.z * inv * wv.z, v.w * inv * wv.w };
    ushort4 h, l;
    split_bf(o[0], h.x, l.x);
    split_bf(o[1], h.y, l.y);
    split_bf(o[2], h.z, l.z);
    split_bf(o[3], h.w, l.w);
    *(ushort4*)(hi + (size_t)t * DM + lane * 4) = h;
    *(ushort4*)(lo + (size_t)t * DM + lane * 4) = l;
}

// f32 RMSNorm (final norm)
__global__ __launch_bounds__(256)
void rmsnorm_kernel(const float* __restrict__ x, const float* __restrict__ w,
                    float* __restrict__ out)
{
    const int wave = threadIdx.x >> 6;
    const int lane = threadIdx.x & 63;
    const int t = blockIdx.x * 4 + wave;
    const float* xp = x + (size_t)t * DM;
    float4 v = *(const float4*)(xp + lane * 4);
    float ss = v.x * v.x + v.y * v.y + v.z * v.z + v.w * v.w;
    #pragma unroll
    for (int off = 1; off < 64; off <<= 1) ss += __shfl_xor(ss, off);
    float inv = rsqrtf(ss * (1.f / DM) + 1e-5f);
    float4 wv = *(const float4*)(w + lane * 4);
    float4 o;
    o.x = v.x * inv * wv.x;
    o.y = v.y * inv * wv.y;
    o.z = v.z * inv * wv.z;
    o.w = v.w * inv * wv.w;
    *(float4*)(out + (size_t)t * DM + lane * 4) = o;
}

// ---------------------------------------------------------------------------
// Causal depthwise conv (K=4) + SiLU
// ---------------------------------------------------------------------------
__global__ __launch_bounds__(256)
void conv_silu_kernel(const float* __restrict__ xm,
                      const float* __restrict__ w,
                      const float* __restrict__ cb,
                      float* __restrict__ xs)
{
    const int idx = blockIdx.x * 256 + threadIdx.x;
    const int d = idx & (DI - 1);
    const int t = idx >> 9;
    const int l = t & (LL - 1);
    float acc = cb[d];
    const float* wp = w + d * 4;
    #pragma unroll
    for (int k = 0; k < 4; ++k) {
        int ll = l + k - 3;
        if (ll >= 0) acc = fmaf(xm[(size_t)(t + k - 3) * DI + d], wp[k], acc);
    }
    xs[idx] = silu_f(acc);
}

// ---------------------------------------------------------------------------
// Chunked parallel selective scan (p1: local scans, p2: combine, p3: rescan)
// ---------------------------------------------------------------------------
__global__ __launch_bounds__(256)
void scan_p1(const float* __restrict__ delta,
             const float* __restrict__ dbc,
             const float* __restrict__ xs,
             const float* __restrict__ A_log,
             float* __restrict__ st,
             float* __restrict__ sdl)
{
    const int blk = blockIdx.x;
    const int dhalf = blk & 1;
    const int chunk = (blk >> 1) & (NCH - 1);
    const int b = blk >> 5;
    const int d = (dhalf << 8) + threadIdx.x;
    const int t0 = b * LL + chunk * CHUNK;

    __shared__ float Bs[CHUNK][DSTATE];
    for (int i = threadIdx.x; i < CHUNK * DSTATE; i += 256) {
        int s = i >> 4, n = i & 15;
        Bs[s][n] = dbc[(size_t)(t0 + s) * 48 + 16 + n];
    }
    __syncthreads();

    float An[16];
    #pragma unroll
    for (int n = 0; n < 16; ++n) An[n] = -__expf(A_log[d * 16 + n]);

    float h[16];
    #pragma unroll
    for (int n = 0; n < 16; ++n) h[n] = 0.f;
    float sumdl = 0.f;

    for (int s = 0; s < CHUNK; ++s) {
        const size_t off = (size_t)(t0 + s) * DI + d;
        const float dl = delta[off];
        const float du = dl * xs[off];
        sumdl += dl;
        #pragma unroll
        for (int n = 0; n < 16; ++n) {
            float a = __expf(dl * An[n]);
            h[n] = fmaf(a, h[n], du * Bs[s][n]);
        }
    }

    const size_t base = ((size_t)(b * NCH + chunk) * DSTATE) * DI + d;
    #pragma unroll
    for (int n = 0; n < 16; ++n) st[base + (size_t)n * DI] = h[n];
    sdl[(size_t)(b * NCH + chunk) * DI + d] = sumdl;
}

__global__ __launch_bounds__(256)
void scan_p2(float* __restrict__ st, const float* __restrict__ sdl,
             const float* __restrict__ A_log)
{
    const int b = blockIdx.x >> 1;
    const int d = ((blockIdx.x & 1) << 8) + threadIdx.x;

    float An[16];
    #pragma unroll
    for (int n = 0; n < 16; ++n) An[n] = -__expf(A_log[d * 16 + n]);

    float H[16];
    #pragma unroll
    for (int n = 0; n < 16; ++n) H[n] = 0.f;

    for (int c = 0; c < NCH; ++c) {
        const size_t base = ((size_t)(b * NCH + c) * DSTATE) * DI + d;
        const float sums = sdl[(size_t)(b * NCH + c) * DI + d];
        #pragma unroll
        for (int n = 0; n < 16; ++n) {
            float fin = st[base + (size_t)n * DI];
            float dec = __expf(An[n] * sums);
            st[base + (size_t)n * DI] = H[n];
            H[n] = fmaf(dec, H[n], fin);
        }
    }
}

__global__ __launch_bounds__(256)
void scan_p3(const float* __restrict__ delta,
             const float* __restrict__ dbc,
             const float* __restrict__ xs,
             const float* __restrict__ res,
             const float* __restrict__ A_log,
             const float* __restrict__ Dp,
             const float* __restrict__ st,
             unsigned short* __restrict__ y_hi,
             unsigned short* __restrict__ y_lo)
{
    const int blk = blockIdx.x;
    const int dhalf = blk & 1;
    const int chunk = (blk >> 1) & (NCH - 1);
    const int b = blk >> 5;
    const int d = (dhalf << 8) + threadIdx.x;
    const int t0 = b * LL + chunk * CHUNK;

    __shared__ float BCs[CHUNK][32];
    for (int i = threadIdx.x; i < CHUNK * 32; i += 256) {
        int s = i >> 5, c = i & 31;
        BCs[s][c] = dbc[(size_t)(t0 + s) * 48 + 16 + c];
    }
    __syncthreads();

    float An[16];
    #pragma unroll
    for (int n = 0; n < 16; ++n) An[n] = -__expf(A_log[d * 16 + n]);
    const float Dv = Dp[d];

    const size_t base = ((size_t)(b * NCH + chunk) * DSTATE) * DI + d;
    float h[16];
    #pragma unroll
    for (int n = 0; n < 16; ++n) h[n] = st[base + (size_t)n * DI];

    for (int s = 0; s < CHUNK; ++s) {
        const size_t off = (size_t)(t0 + s) * DI + d;
        const float dl = delta[off];
        const float xv = xs[off];
        const float rv = res[off];
        const float du = dl * xv;
        float acc = 0.f;
        #pragma unroll
        for (int n = 0; n < 16; ++n) {
            float a = __expf(dl * An[n]);
            h[n] = fmaf(a, h[n], du * BCs[s][n]);
            acc  = fmaf(h[n], BCs[s][16 + n], acc);
        }
        float y = fmaf(xv, Dv, acc) * silu_f(rv);
        unsigned short hh, ll;
        split_bf(y, hh, ll);
        y_hi[off] = hh;
        y_lo[off] = ll;
    }
}

// ---------------------------------------------------------------------------
// Final head helpers
// ---------------------------------------------------------------------------
__global__ void zero_kernel(float* __restrict__ p, int n)
{
    int i = blockIdx.x * 256 + threadIdx.x;
    if (i < n) p[i] = 0.f;
}

__global__ __launch_bounds__(256)
void hmean_kernel(const float* __restrict__ hn, float* __restrict__ hmean)
{
    const int b = blockIdx.x >> 4;
    const int lc = blockIdx.x & 15;
    const int d = threadIdx.x;
    float s = 0.f;
    for (int l = lc * 64; l < lc * 64 + 64; ++l)
        s += hn[((size_t)(b * LL + l)) * DM + d];
    atomicAdd(&hmean[b * DM + d], s * (1.f / LL));
}

__global__ __launch_bounds__(256)
void mlp_kernel(const float* __restrict__ feat, const float* __restrict__ W1,
                const float* __restrict__ b1, const float* __restrict__ W2,
                const float* __restrict__ b2, float* __restrict__ out)
{
    __shared__ float hid[BB][MID + 2];
    const int tid = threadIdx.x;
    for (int idx = tid; idx < BB * MID; idx += 256) {
        int b = idx / MID, m = idx % MID;
        float s = b1[m];
        for (int k = 0; k < OUT_DIM; ++k)
            s = fmaf(feat[b * OUT_DIM + k], W1[m * OUT_DIM + k], s);
        hid[b][m] = fmaxf(s, 0.f);
    }
    __syncthreads();
    if (tid < BB * NCLS) {
        int b = tid / NCLS, c = tid % NCLS;
        float s = b2[c];
        for (int k = 0; k < MID; ++k)
            s = fmaf(hid[b][k], W2[c * MID + k], s);
        out[b * NCLS + c] = s;
    }
}

// ---------------------------------------------------------------------------
extern "C" void kernel_launch(void* const* d_in, const int* in_sizes, int n_in,
                              void* d_out, int out_size, void* d_ws, size_t ws_size,
                              hipStream_t stream)
{
    const float* x       = (const float*)d_in[0];
    const float* emb_W   = (const float*)d_in[1];
    const float* emb_b   = (const float*)d_in[2];
    const float* in_W    = (const float*)d_in[3];
    const float* conv_W  = (const float*)d_in[4];
    const float* conv_b  = (const float*)d_in[5];
    const float* xp_W    = (const float*)d_in[6];
    const float* dt_W    = (const float*)d_in[7];
    const float* dt_b    = (const float*)d_in[8];
    const float* A_log   = (const float*)d_in[9];
    const float* Dp      = (const float*)d_in[10];
    const float* out_W   = (const float*)d_in[11];
    const float* norm_W  = (const float*)d_in[12];
    const float* normf_W = (const float*)d_in[13];
    const float* head_W  = (const float*)d_in[14];
    const float* head_b  = (const float*)d_in[15];
    const float* W1      = (const float*)d_in[16];
    const float* b1      = (const float*)d_in[17];
    const float* W2      = (const float*)d_in[18];
    const float* b2      = (const float*)d_in[19];

    const size_t TM = (size_t)T_TOK * DM;   // 4.19M
    const size_t TD = (size_t)T_TOK * DI;   // 8.39M

    float* ws    = (float*)d_ws;
    float* h     = ws;
    float* hn    = h   + TM;     // also aliases st/sdl during layers
    float* xm    = hn  + TM;     // also aliases delta
    float* res   = xm  + TD;
    float* xs    = res + TD;
    float* dbc   = xs  + TD;
    float* hmean = dbc + (size_t)T_TOK * 48;
    float* feat  = hmean + BB * DM;
    float* planes = feat + BB * OUT_DIM;         // 8.39M floats (bf16 plane region)
    float* wplanes = planes + TD;                // weight planes

    float* delta = xm;
    float* st  = hn;
    float* sdl = hn + (size_t)BB * NCH * DSTATE * DI;

    // activation planes (time-multiplexed region):
    unsigned short* y_hi  = (unsigned short*)planes;          // [T][DI]
    unsigned short* y_lo  = y_hi + TD;
    unsigned short* hn_hi = (unsigned short*)planes;          // [T][DM] (disjoint in time)
    unsigned short* hn_lo = hn_hi + TM;
    unsigned short* x_hi  = (unsigned short*)planes;          // [T][64] (embed only)
    unsigned short* x_lo  = x_hi + (size_t)T_TOK * IN_FEAT;

    // weight planes (persist across whole launch):
    unsigned short* embW_hi = (unsigned short*)wplanes;
    unsigned short* embW_lo = embW_hi + (size_t)DM * IN_FEAT;
    unsigned short* inW_hi  = embW_lo + (size_t)DM * IN_FEAT;
    unsigned short* inW_lo  = inW_hi + (size_t)NL * 2 * DI * DM;
    unsigned short* outW_hi = inW_lo + (size_t)NL * 2 * DI * DM;
    unsigned short* outW_lo = outW_hi + (size_t)NL * DM * DI;

    dim3 blk(256);

    // Weight + input splitting
    split4_kernel<<<(DM * IN_FEAT / 4 + 255) / 256, blk, 0, stream>>>(
        emb_W, embW_hi, embW_lo, DM * IN_FEAT / 4);
    split4_kernel<<<(NL * 2 * DI * DM / 4 + 255) / 256, blk, 0, stream>>>(
        in_W, inW_hi, inW_lo, NL * 2 * DI * DM / 4);
    split4_kernel<<<(NL * DM * DI / 4 + 255) / 256, blk, 0, stream>>>(
        out_W, outW_hi, outW_lo, NL * DM * DI / 4);
    split4_kernel<<<(T_TOK * IN_FEAT / 4 + 255) / 256, blk, 0, stream>>>(
        x, x_hi, x_lo, T_TOK * IN_FEAT / 4);

    // Embed: h = x @ emb_W^T + emb_b
    gemm_bf16x3<false, true, false><<<dim3(DM / 128, T_TOK / 128), blk, 0, stream>>>(
        x_hi, x_lo, embW_hi, embW_lo, emb_b,
        h, DM, h, DM, DM, T_TOK, DM, IN_FEAT);

    for (int i = 0; i < NL; ++i) {
        // hn planes = rmsnorm(h) in bf16 hi/lo
        rmsnorm_bf16_kernel<<<T_TOK / 4, blk, 0, stream>>>(
            h, norm_W + i * DM, hn_hi, hn_lo);

        // xr = hn @ in_W[i]^T -> split xm | res   (f32 outputs)
        gemm_bf16x3<false, false, true><<<dim3(2 * DI / 128, T_TOK / 128), blk, 0, stream>>>(
            hn_hi, hn_lo,
            inW_hi + (size_t)i * 2 * DI * DM, inW_lo + (size_t)i * 2 * DI * DM,
            nullptr, xm, DI, res, DI, DI, T_TOK, 2 * DI, DM);

        // xs = silu(causal_dwconv(xm))
        conv_silu_kernel<<<(T_TOK * DI) / 256, blk, 0, stream>>>(
            xm, conv_W + (size_t)i * DI * DCONV, conv_b + i * DI, xs);

        // dbc = xs @ xp_W[i]^T   [T,48]
        gemm_f32<0, false><<<dim3(1, T_TOK / 64), blk, 0, stream>>>(
            xs, DI, xp_W + (size_t)i * 48 * DI, nullptr,
            dbc, 48, dbc, 48, 48, T_TOK, 48, DI);

        // delta = softplus(dlt @ dt_W[i]^T + dt_b[i])
        gemm_f32<1, false><<<dim3(DI / 64, T_TOK / 64), blk, 0, stream>>>(
            dbc, 48, dt_W + (size_t)i * DI * DTRANK, dt_b + i * DI,
            delta, DI, delta, DI, DI, T_TOK, DI, DTRANK);

        // chunked parallel selective scan; y emitted as bf16 hi/lo planes
        const float* Al = A_log + (size_t)i * DI * DSTATE;
        scan_p1<<<BB * NCH * 2, blk, 0, stream>>>(delta, dbc, xs, Al, st, sdl);
        scan_p2<<<32, blk, 0, stream>>>(st, sdl, Al);
        scan_p3<<<BB * NCH * 2, blk, 0, stream>>>(delta, dbc, xs, res, Al,
                                                  Dp + i * DI, st, y_hi, y_lo);

        // h += y @ out_W[i]^T
        gemm_bf16x3<true, false, false><<<dim3(DM / 128, T_TOK / 128), blk, 0, stream>>>(
            y_hi, y_lo,
            outW_hi + (size_t)i * DM * DI, outW_lo + (size_t)i * DM * DI,
            nullptr, h, DM, h, DM, DM, T_TOK, DM, DI);
    }

    // Final norm + head (mean over L commutes with linear head)
    rmsnorm_kernel<<<T_TOK / 4, blk, 0, stream>>>(h, normf_W, hn);
    zero_kernel<<<(BB * DM + 255) / 256, blk, 0, stream>>>(hmean, BB * DM);
    hmean_kernel<<<256, blk, 0, stream>>>(hn, hmean);
    gemm_f32<0, false><<<dim3(2, 1), blk, 0, stream>>>(
        hmean, DM, head_W, head_b, feat, OUT_DIM, feat, OUT_DIM, OUT_DIM,
        BB, OUT_DIM, DM);
    mlp_kernel<<<1, blk, 0, stream>>>(feat, W1, b1, W2, b2, (float*)d_out);
}